// Round 1
// baseline (201.262 us; speedup 1.0000x reference)
//
#include <hip/hip_runtime.h>

// Problem constants
// x: [2,64,32,32,32] f32 | weight: [128,64,3,3,3] f32 | bias:[128]
// lora_A: [16,1728] | lora_B: [128,16] | out: [2,128,32,32,32] f32
// SCALING = 2.0

typedef __attribute__((ext_vector_type(8))) short short8;
typedef __attribute__((ext_vector_type(4))) float float4v;

__device__ inline unsigned short f2bf(float f) {
    unsigned int u = __float_as_uint(f);
    unsigned int r = u + 0x7FFFu + ((u >> 16) & 1u);
    return (unsigned short)(r >> 16);
}

// P1: x [b,c,p] f32  ->  xt [b,p,c] bf16   (p = d*1024+h*32+w, 32768 per batch)
__global__ __launch_bounds__(256) void transpose_kernel(const float* __restrict__ x,
                                                        unsigned short* __restrict__ xt) {
    __shared__ float tile[64][65];
    int t = threadIdx.x;
    int blk = blockIdx.x;            // 1024 blocks: 2 b * 512 p-tiles
    int b = blk >> 9;
    int p0 = (blk & 511) * 64;
#pragma unroll
    for (int it = 0; it < 16; ++it) {
        int idx = it * 256 + t;
        int c = idx >> 6, pp = idx & 63;
        tile[c][pp] = x[((size_t)(b * 64 + c) << 15) + p0 + pp];
    }
    __syncthreads();
#pragma unroll
    for (int it = 0; it < 8; ++it) {
        int idx = it * 256 + t;
        int pp = idx >> 5, cp = idx & 31;   // cp = channel pair
        unsigned int u0 = f2bf(tile[cp * 2][pp]);
        unsigned int u1 = f2bf(tile[cp * 2 + 1][pp]);
        *(unsigned int*)(xt + ((size_t)((b << 15) + p0 + pp) * 64 + cp * 2)) =
            u0 | (u1 << 16);
    }
}

// P2: build Wc_t[144][1728] bf16, k = off*64 + c
//   n<128:  weight[n][c][off]  (weight flat: (n*64+c)*27 + off)
//   n>=128: lora_A[n-128][c*27 + off]
__global__ void wct_kernel(const float* __restrict__ weight,
                           const float* __restrict__ loraA,
                           unsigned short* __restrict__ wct) {
    int n = blockIdx.y;
    int k = blockIdx.x * 64 + threadIdx.x;   // grid.x = 27, block = 64
    int off = k >> 6;
    int c = k & 63;
    float v;
    if (n < 128) v = weight[(n * 64 + c) * 27 + off];
    else         v = loraA[(n - 128) * 1728 + c * 27 + off];
    wct[n * 1728 + k] = f2bf(v);
}

// K1: implicit GEMM. D[o(144)][p] = sum_k Wc_t[o][k] * cols[p][k]
//   A-operand = weights (M=144 in 9 frags), B-operand = cols (N=16 per wave).
//   Block: 256 thr = 4 waves, 64 positions (wave w -> 16 pos), K loop 27x64.
//   Epilogue: o<128 -> out (+bias), o>=128 -> low workspace.
__global__ __launch_bounds__(256) void gemm_kernel(const unsigned short* __restrict__ xt,
                                                   const unsigned short* __restrict__ wct,
                                                   const float* __restrict__ bias,
                                                   float* __restrict__ out,
                                                   float* __restrict__ low) {
    __shared__ unsigned short Alds[64 * 72];    // cols tile [p][k64], pad 72
    __shared__ unsigned short Blds[144 * 72];   // weight tile [n][k64], pad 72

    int t = threadIdx.x;
    int wv = t >> 6;
    int lane = t & 63;
    int l16 = lane & 15;
    int quad = lane >> 4;

    int bm = blockIdx.x;             // 1024 blocks
    int b = bm >> 9;
    int tt = bm & 511;               // 64-position tile within batch
    int d = tt >> 4;
    int h0 = (tt & 15) * 2;

    float4v acc[9];
#pragma unroll
    for (int nf = 0; nf < 9; ++nf) acc[nf] = (float4v){0.f, 0.f, 0.f, 0.f};

    for (int kb = 0; kb < 27; ++kb) {
        int ki = kb / 9, kj = (kb / 3) % 3, kl = kb % 3;
        int sd = d + ki - 1;
        __syncthreads();
        // stage cols tile: 64 pos x 64 ch, 16B per thread-chunk
        for (int ch = t; ch < 512; ch += 256) {
            int pi = ch >> 3, c8 = ch & 7;
            int sh = h0 + (pi >> 5) + kj - 1;
            int sw = (pi & 31) + kl - 1;
            uint4 v = {0u, 0u, 0u, 0u};
            if ((unsigned)sd < 32u && (unsigned)sh < 32u && (unsigned)sw < 32u) {
                v = *(const uint4*)(xt + ((size_t)((((b * 32 + sd) * 32 + sh) * 32 + sw)) * 64 + c8 * 8));
            }
            *(uint4*)(&Alds[pi * 72 + c8 * 8]) = v;
        }
        // stage weight tile: 144 n x 64 k
        for (int ch = t; ch < 1152; ch += 256) {
            int n = ch >> 3, c8 = ch & 7;
            *(uint4*)(&Blds[n * 72 + c8 * 8]) =
                *(const uint4*)(wct + ((size_t)n * 1728 + kb * 64 + c8 * 8));
        }
        __syncthreads();
#pragma unroll
        for (int ks = 0; ks < 2; ++ks) {
            int koff = ks * 32 + quad * 8;
            short8 bfrag = *(const short8*)(&Alds[(wv * 16 + l16) * 72 + koff]);
#pragma unroll
            for (int nf = 0; nf < 9; ++nf) {
                short8 afrag = *(const short8*)(&Blds[(nf * 16 + l16) * 72 + koff]);
                acc[nf] = __builtin_amdgcn_mfma_f32_16x16x32_bf16(afrag, bfrag, acc[nf], 0, 0, 0);
            }
        }
    }

    int p = tt * 64 + wv * 16 + l16;      // flat spatial position in batch
#pragma unroll
    for (int nf = 0; nf < 9; ++nf) {
#pragma unroll
        for (int r = 0; r < 4; ++r) {
            int o = nf * 16 + quad * 4 + r;
            float v = acc[nf][r];
            if (o < 128) out[((size_t)(b * 128 + o) << 15) + p] = v + bias[o];
            else         low[((size_t)(b * 16 + (o - 128)) << 15) + p] = v;
        }
    }
}

// K2: foldlow[r][p] = 27-neighborhood sum of low (cropped at bounds);
//     out[b,o,p] += 2.0 * sum_r lora_B[o,r] * foldlow[r][p]
__global__ __launch_bounds__(256) void fold_mix_kernel(const float* __restrict__ low,
                                                       const float* __restrict__ loraB,
                                                       float* __restrict__ out) {
    __shared__ float lB[2048];
    int t = threadIdx.x;
    for (int idx = t; idx < 2048; idx += 256) lB[idx] = loraB[idx];
    __syncthreads();

    int gp = blockIdx.x * 256 + t;       // 256 blocks
    int b = gp >> 15;
    int p = gp & 32767;
    int d = p >> 10, h = (p >> 5) & 31, w = p & 31;

    float fl[16];
#pragma unroll
    for (int r = 0; r < 16; ++r) fl[r] = 0.f;

    for (int dd = -1; dd <= 1; ++dd) {
        int sd = d + dd;
        if ((unsigned)sd >= 32u) continue;
        for (int dh = -1; dh <= 1; ++dh) {
            int sh = h + dh;
            if ((unsigned)sh >= 32u) continue;
            for (int dw = -1; dw <= 1; ++dw) {
                int sw = w + dw;
                if ((unsigned)sw >= 32u) continue;
                const float* lp = low + ((size_t)b << 19) + (sd << 10) + (sh << 5) + sw;
#pragma unroll
                for (int r = 0; r < 16; ++r) fl[r] += lp[(size_t)r << 15];
            }
        }
    }

    float* op = out + ((size_t)(b * 128) << 15) + p;
    for (int o = 0; o < 128; ++o) {
        float s = 0.f;
#pragma unroll
        for (int r = 0; r < 16; ++r) s += lB[o * 16 + r] * fl[r];
        op[(size_t)o << 15] += 2.0f * s;
    }
}

extern "C" void kernel_launch(void* const* d_in, const int* in_sizes, int n_in,
                              void* d_out, int out_size, void* d_ws, size_t ws_size,
                              hipStream_t stream) {
    const float* x      = (const float*)d_in[0];
    const float* weight = (const float*)d_in[1];
    const float* bias   = (const float*)d_in[2];
    const float* loraA  = (const float*)d_in[3];
    const float* loraB  = (const float*)d_in[4];
    float* out = (float*)d_out;

    char* ws = (char*)d_ws;
    unsigned short* xt  = (unsigned short*)ws;                    // 2*32768*64*2  = 8,388,608 B
    unsigned short* wct = (unsigned short*)(ws + 8388608);        // 144*1728*2    =   497,664 B
    float* low          = (float*)(ws + 8388608 + 497664);        // 2*16*32768*4  = 4,194,304 B

    hipLaunchKernelGGL(transpose_kernel, dim3(1024), dim3(256), 0, stream, x, xt);
    hipLaunchKernelGGL(wct_kernel, dim3(27, 144), dim3(64), 0, stream, weight, loraA, wct);
    hipLaunchKernelGGL(gemm_kernel, dim3(1024), dim3(256), 0, stream, xt, wct, bias, out, low);
    hipLaunchKernelGGL(fold_mix_kernel, dim3(256), dim3(256), 0, stream, low, loraB, out);
}